// Round 4
// baseline (348.081 us; speedup 1.0000x reference)
//
#include <hip/hip_runtime.h>

#define B_ 4
#define C_ 256
#define CI_ 128
#define HW_ 4096
#define KS_ 4

typedef _Float16 f16x8 __attribute__((ext_vector_type(8)));
typedef _Float16 f16x4 __attribute__((ext_vector_type(4)));
typedef float f32x16 __attribute__((ext_vector_type(16)));
typedef float f32x4 __attribute__((ext_vector_type(4)));

__device__ __forceinline__ f32x16 mfma16(f16x8 a, f16x8 b, f32x16 c) {
  return __builtin_amdgcn_mfma_f32_32x32x16_f16(a, b, c, 0, 0, 0);
}
__device__ __forceinline__ f16x8 cat8(f16x4 a, f16x4 b) {
  return __builtin_shufflevector(a, b, 0, 1, 2, 3, 4, 5, 6, 7);
}

// Packed layouts (all MFMA operands):
//  16B granule: off16 = ((row>>5)*(K/8) + k8)*32 + (row&31); f16 idx = off16*8
//   8B granule: off8  = ((row>>5)*(K/4) + k4)*32 + (row&31); f16 idx = off8*4
// gP uses row=ci, k=key: off8 = (ciblk*(HW/4) + key4)*32 + (ci&31)

// ---------------- K0a: x (b,ch,sp) fp32 -> xP packed (row=sp, k=ch, 16B) ----------------
__global__ __launch_bounds__(256) void k0_transpose(const float* __restrict__ x,
                                                    _Float16* __restrict__ xP) {
  __shared__ _Float16 Lt[64 * 66];
  int t = threadIdx.x;
  int sp0 = blockIdx.x * 64;
  int ch0 = blockIdx.y * 64;
  int b = blockIdx.z;
  const float* xb = x + (size_t)b * C_ * HW_;
#pragma unroll
  for (int i = 0; i < 16; ++i) {
    int ch = i * 4 + (t >> 6);
    int sp = t & 63;
    Lt[ch * 66 + sp] = (_Float16)xb[(size_t)(ch0 + ch) * HW_ + sp0 + sp];
  }
  __syncthreads();
  _Float16* xPb = xP + (size_t)b * HW_ * C_;
  int l31 = t & 31;
  int c8 = t >> 5;  // 0..7
#pragma unroll
  for (int sph = 0; sph < 2; ++sph) {
    int spl = sph * 32 + l31;
    f16x8 v;
#pragma unroll
    for (int i = 0; i < 8; ++i) v[i] = Lt[(c8 * 8 + i) * 66 + spl];
    int sp = sp0 + spl;
    size_t off16 = ((size_t)(sp >> 5) * (C_ / 8) + (ch0 / 8 + c8)) * 32 + (sp & 31);
    *(f16x8*)&xPb[off16 * 8] = v;
  }
}

// ---------------- K0b: weights fp32 -> packed fp16 [theta|phi|g|out] ----------------
__global__ __launch_bounds__(256) void k0_wconv(const float* __restrict__ tw,
                                                const float* __restrict__ pw,
                                                const float* __restrict__ gw,
                                                const float* __restrict__ ow,
                                                _Float16* __restrict__ w16) {
  int g = blockIdx.x * 256 + threadIdx.x;  // 16384 chunks of 16B
  int ti = g >> 12;
  int local = g & 4095;
  const float* src = (ti == 0) ? tw : (ti == 1) ? pw : (ti == 2) ? gw : ow;
  int row, col;
  if (ti < 3) {  // 128 rows x 256 k
    int r31 = local & 31, k8 = (local >> 5) & 31, rblk = local >> 10;
    row = rblk * 32 + r31;
    col = k8 * 8;
    src += (size_t)row * 256 + col;
  } else {  // 256 rows x 128 k
    int r31 = local & 31, k8 = (local >> 5) & 15, rblk = local >> 9;
    row = rblk * 32 + r31;
    col = k8 * 8;
    src += (size_t)row * 128 + col;
  }
  f32x4 a = *(const f32x4*)src;
  f32x4 c = *(const f32x4*)(src + 4);
  f16x8 hv;
#pragma unroll
  for (int j = 0; j < 4; ++j) {
    hv[j] = (_Float16)a[j];
    hv[j + 4] = (_Float16)c[j];
  }
  *(f16x8*)&w16[(size_t)ti * 32768 + (size_t)local * 8] = hv;
}

// ---------------- K1: projections -> thetaP/phiP (row=q, k=ci, 8B), gP (row=ci, k=key, 8B) --
__global__ __launch_bounds__(256, 2) void k1_proj(
    const _Float16* __restrict__ xP, const _Float16* __restrict__ w16,
    const float* __restrict__ tb, const float* __restrict__ pb,
    const float* __restrict__ gb, _Float16* __restrict__ thetaP,
    _Float16* __restrict__ phiP, _Float16* __restrict__ gP) {
  int p = blockIdx.y;
  int b = blockIdx.z;
  int sp0 = blockIdx.x * 64;
  int tid = threadIdx.x;
  int w = tid >> 6;
  int lane = tid & 63;
  int l31 = lane & 31;
  int h = lane >> 5;
  const _Float16* xPb = xP + (size_t)b * HW_ * C_;
  f32x16 acc[2];
#pragma unroll
  for (int i = 0; i < 2; ++i)
#pragma unroll
    for (int j = 0; j < 16; ++j) acc[i][j] = 0.f;

  if (p < 2) {
    int wsp = w & 1, wci = w >> 1;
    const _Float16* W = w16 + (size_t)p * 32768;
#pragma unroll
    for (int ks = 0; ks < 16; ++ks) {
      int k8 = ks * 2 + h;
      f16x8 bf = *(const f16x8*)&xPb[((((sp0 >> 5) + wsp) * 32 + k8) * 32 + l31) * 8];
#pragma unroll
      for (int mt = 0; mt < 2; ++mt) {
        f16x8 af = *(const f16x8*)&W[((((wci * 2 + mt) * 32) + k8) * 32 + l31) * 8];
        acc[mt] = mfma16(af, bf, acc[mt]);
      }
    }
    const float* bias = (p == 0) ? tb : pb;
    _Float16* out = ((p == 0) ? thetaP : phiP) + (size_t)b * HW_ * CI_;
    int sp = sp0 + wsp * 32 + l31;
#pragma unroll
    for (int mt = 0; mt < 2; ++mt)
#pragma unroll
      for (int g4 = 0; g4 < 4; ++g4) {
        int cb = (wci * 2 + mt) * 32 + g4 * 8 + h * 4;
        f32x4 bv = *(const f32x4*)&bias[cb];
        f16x4 res;
#pragma unroll
        for (int j = 0; j < 4; ++j) res[j] = (_Float16)(acc[mt][g4 * 4 + j] + bv[j]);
        size_t off8 = ((size_t)(sp >> 5) * (CI_ / 4) + (cb >> 2)) * 32 + (sp & 31);
        *(f16x4*)&out[off8 * 4] = res;
      }
  } else {
    int wci = w;  // 0..3
    const _Float16* W = w16 + 2 * 32768;
#pragma unroll
    for (int ks = 0; ks < 16; ++ks) {
      int k8 = ks * 2 + h;
      f16x8 bf = *(const f16x8*)&W[((wci * 32 + k8) * 32 + l31) * 8];
#pragma unroll
      for (int mt = 0; mt < 2; ++mt) {
        f16x8 af = *(const f16x8*)&xPb[((((sp0 >> 5) + mt) * 32 + k8) * 32 + l31) * 8];
        acc[mt] = mfma16(af, bf, acc[mt]);
      }
    }
    float bv = gb[wci * 32 + l31];
    _Float16* out = gP + (size_t)b * CI_ * HW_;
#pragma unroll
    for (int mt = 0; mt < 2; ++mt)
#pragma unroll
      for (int g4 = 0; g4 < 4; ++g4) {
        int key4 = (sp0 >> 2) + mt * 8 + g4 * 2 + h;
        f16x4 res;
#pragma unroll
        for (int j = 0; j < 4; ++j) res[j] = (_Float16)(acc[mt][g4 * 4 + j] + bv);
        size_t off8 = ((size_t)wci * (HW_ / 4) + key4) * 32 + l31;
        *(f16x4*)&out[off8 * 4] = res;
      }
  }
}

// ---------------- K2: flash attention, 128q x 1024key per block, LDS-staged tiles -------
__global__ __launch_bounds__(256, 3) void k2_attn(
    const _Float16* __restrict__ thetaP, const _Float16* __restrict__ phiP,
    const _Float16* __restrict__ gP, _Float16* __restrict__ Opart,
    float* __restrict__ ml) {
  __shared__ _Float16 ldsPhi[8192];  // 16 KB: 64 keys x 128 ci, packed
  __shared__ _Float16 ldsG[8192];    // 16 KB: 128 ci x 64 keys, packed
  __shared__ _Float16 Pl[4 * 32 * 72];
  int s = blockIdx.y;
  int b = blockIdx.z;
  int q0 = blockIdx.x * 128;
  int tid = threadIdx.x;
  int w = tid >> 6;
  int lane = tid & 63;
  int l31 = lane & 31;
  int h = lane >> 5;
  int qblk = (q0 >> 5) + w;
  const _Float16* thb = thetaP + (size_t)b * HW_ * CI_;
  const _Float16* phb = phiP + (size_t)b * HW_ * CI_;
  const _Float16* gvb = gP + (size_t)b * CI_ * HW_;

  f16x8 Bq[8];
#pragma unroll
  for (int ks = 0; ks < 8; ++ks) {
    f16x4 lo = *(const f16x4*)&thb[(((size_t)qblk * 32 + ks * 4 + h * 2) * 32 + l31) * 4];
    f16x4 hi = *(const f16x4*)&thb[(((size_t)qblk * 32 + ks * 4 + h * 2 + 1) * 32 + l31) * 4];
    Bq[ks] = cat8(lo, hi);
  }

  f32x16 o[4];
#pragma unroll
  for (int i = 0; i < 4; ++i)
#pragma unroll
    for (int j = 0; j < 16; ++j) o[i][j] = 0.f;
  float m_run = -1e30f, l_run = 0.f;
  _Float16* Plw = &Pl[w * 32 * 72];

  for (int t = 0; t < 16; ++t) {  // 16 x 64 = 1024 keys per split (bugfix: was 8)
    int kb = s * 1024 + t * 64;
    // ---- stage phi (16KB) + g (16KB) tiles, coalesced linear copies ----
    {
      const _Float16* phiSrc = phb + (size_t)(kb >> 5) * 4096;  // f16 units
#pragma unroll
      for (int i = 0; i < 8; ++i) {
        int c = w * 8 + i;
        if (c < 16) {
          *(f16x8*)&ldsPhi[c * 512 + lane * 8] =
              *(const f16x8*)&phiSrc[c * 512 + lane * 8];
        } else {
          int j = c - 16;
          int seg = j >> 2, wi = j & 3;
          *(f16x8*)&ldsG[j * 512 + lane * 8] = *(const f16x8*)&gvb[
              ((size_t)seg * (HW_ / 4) + (kb >> 2)) * 128 + wi * 512 + lane * 8];
        }
      }
    }
    __syncthreads();
    // ---- QK^T (S^T): A = phi rows (key), B = theta (q) ----
    f32x16 sT[2];
#pragma unroll
    for (int i = 0; i < 2; ++i)
#pragma unroll
      for (int j = 0; j < 16; ++j) sT[i][j] = 0.f;
#pragma unroll
    for (int ks = 0; ks < 8; ++ks) {
#pragma unroll
      for (int mt = 0; mt < 2; ++mt) {
        const _Float16* pb2 = ldsPhi + mt * 4096;
        f16x4 lo = *(const f16x4*)&pb2[((ks * 4 + h * 2) * 32 + l31) * 4];
        f16x4 hi = *(const f16x4*)&pb2[((ks * 4 + h * 2 + 1) * 32 + l31) * 4];
        sT[mt] = mfma16(cat8(lo, hi), Bq[ks], sT[mt]);
      }
    }
    // ---- online softmax (per q = lane col; keys split across regs) ----
    float vmax = -1e30f;
#pragma unroll
    for (int mt = 0; mt < 2; ++mt)
#pragma unroll
      for (int r = 0; r < 16; ++r) vmax = fmaxf(vmax, sT[mt][r]);
    vmax = fmaxf(vmax, __shfl_xor(vmax, 32, 64));
    float m_new = fmaxf(m_run, vmax);
    float alpha = __expf(m_run - m_new);
    float psum = 0.f;
#pragma unroll
    for (int mt = 0; mt < 2; ++mt)
#pragma unroll
      for (int r = 0; r < 16; ++r) {
        float pv = __expf(sT[mt][r] - m_new);
        sT[mt][r] = pv;
        psum += pv;
      }
    psum += __shfl_xor(psum, 32, 64);
    l_run = l_run * alpha + psum;
    m_run = m_new;
#pragma unroll
    for (int i = 0; i < 4; ++i)
#pragma unroll
      for (int j = 0; j < 16; ++j) o[i][j] *= alpha;
    // ---- pack P^T into per-wave LDS [q][key] ----
#pragma unroll
    for (int mt = 0; mt < 2; ++mt)
#pragma unroll
      for (int g4 = 0; g4 < 4; ++g4) {
        f16x4 pk;
#pragma unroll
        for (int j = 0; j < 4; ++j) pk[j] = (_Float16)sT[mt][g4 * 4 + j];
        *(f16x4*)&Plw[l31 * 72 + mt * 32 + g4 * 8 + h * 4] = pk;
      }
    asm volatile("s_waitcnt lgkmcnt(0)" ::: "memory");
    // ---- PV: O^T += g (ci) x P^T (q) ----
#pragma unroll
    for (int kv = 0; kv < 4; ++kv) {
      f16x8 bp = *(const f16x8*)&Plw[l31 * 72 + kv * 16 + h * 8];
#pragma unroll
      for (int mt2 = 0; mt2 < 4; ++mt2) {
        const _Float16* gb2 = ldsG + mt2 * 2048;
        f16x4 lo = *(const f16x4*)&gb2[((kv * 4 + h * 2) * 32 + l31) * 4];
        f16x4 hi = *(const f16x4*)&gb2[((kv * 4 + h * 2 + 1) * 32 + l31) * 4];
        o[mt2] = mfma16(cat8(lo, hi), bp, o[mt2]);
      }
    }
    __syncthreads();
  }
  // ---- epilogue: normalized partial O in packed (row=q, k=ci, 8B) layout ----
  float inv = 1.f / l_run;
  int S = b * KS_ + s;
  size_t obase = (size_t)S * (HW_ * CI_ / 4);
#pragma unroll
  for (int mt2 = 0; mt2 < 4; ++mt2)
#pragma unroll
    for (int g4 = 0; g4 < 4; ++g4) {
      f16x4 res;
#pragma unroll
      for (int j = 0; j < 4; ++j) res[j] = (_Float16)(o[mt2][g4 * 4 + j] * inv);
      int ci4 = mt2 * 8 + g4 * 2 + h;
      size_t off8 = obase + ((size_t)qblk * 32 + ci4) * 32 + l31;
      *(f16x4*)&Opart[off8 * 4] = res;
    }
  if (h == 0) {
    int q = qblk * 32 + l31;
    *(float2*)&ml[((size_t)S * HW_ + q) * 2] = make_float2(m_run, l_run);
  }
}

// ---------------- K2m: merge KS_ splits -> attnP (row=q, k=ci, 16B) ----------------
__global__ __launch_bounds__(256) void k2_merge(const _Float16* __restrict__ Opart,
                                                const float* __restrict__ ml,
                                                _Float16* __restrict__ attnP) {
  int g = blockIdx.x * 256 + threadIdx.x;  // 2^18 chunks
  int q31 = g & 31;
  int ci8 = (g >> 5) & 15;
  int qblk = (g >> 9) & 127;
  int b = g >> 16;
  int q = qblk * 32 + q31;
  float m[KS_], l[KS_], M = -1e30f;
#pragma unroll
  for (int s = 0; s < KS_; ++s) {
    float2 v = *(const float2*)&ml[((size_t)(b * KS_ + s) * HW_ + q) * 2];
    m[s] = v.x;
    l[s] = v.y;
    M = fmaxf(M, m[s]);
  }
  float den = 0.f, wgt[KS_];
#pragma unroll
  for (int s = 0; s < KS_; ++s) {
    wgt[s] = __expf(m[s] - M) * l[s];
    den += wgt[s];
  }
  float inv = 1.f / den;
  f32x4 a0 = {0.f, 0.f, 0.f, 0.f}, a1 = {0.f, 0.f, 0.f, 0.f};
#pragma unroll
  for (int s = 0; s < KS_; ++s) {
    size_t base = (size_t)(b * KS_ + s) * (HW_ * CI_ / 4) +
                  ((size_t)qblk * 32 + ci8 * 2) * 32 + q31;
    f16x4 v0 = *(const f16x4*)&Opart[base * 4];
    f16x4 v1 = *(const f16x4*)&Opart[(base + 32) * 4];
#pragma unroll
    for (int j = 0; j < 4; ++j) {
      a0[j] += wgt[s] * (float)v0[j];
      a1[j] += wgt[s] * (float)v1[j];
    }
  }
  f16x8 res;
#pragma unroll
  for (int j = 0; j < 4; ++j) {
    res[j] = (_Float16)(a0[j] * inv);
    res[j + 4] = (_Float16)(a1[j] * inv);
  }
  size_t off16 = (size_t)b * (HW_ * CI_ / 8) + ((size_t)qblk * 16 + ci8) * 32 + q31;
  *(f16x8*)&attnP[off16 * 8] = res;
}

// ---------------- K3: out conv + BN stat atomics ----------------
__global__ __launch_bounds__(256, 2) void k3_outconv(
    const _Float16* __restrict__ attnP, const _Float16* __restrict__ wo,
    const float* __restrict__ ob, float* __restrict__ oc,
    float* __restrict__ bnsum) {
  int b = blockIdx.z;
  int c0 = blockIdx.y * 128;
  int s0 = blockIdx.x * 64;
  int tid = threadIdx.x;
  int w = tid >> 6;
  int lane = tid & 63;
  int l31 = lane & 31;
  int h = lane >> 5;
  int wsp = w & 1, wc = w >> 1;
  const _Float16* ab = attnP + (size_t)b * HW_ * CI_;
  f32x16 acc[2];
#pragma unroll
  for (int i = 0; i < 2; ++i)
#pragma unroll
    for (int j = 0; j < 16; ++j) acc[i][j] = 0.f;
#pragma unroll
  for (int ks = 0; ks < 8; ++ks) {
    int k8 = ks * 2 + h;
    f16x8 bf = *(const f16x8*)&ab[((((s0 >> 5) + wsp) * 16 + k8) * 32 + l31) * 8];
#pragma unroll
    for (int mt = 0; mt < 2; ++mt) {
      int rblk = (c0 >> 5) + (wc * 2 + mt);
      f16x8 af = *(const f16x8*)&wo[((rblk * 16 + k8) * 32 + l31) * 8];
      acc[mt] = mfma16(af, bf, acc[mt]);
    }
  }
  int sp = s0 + wsp * 32 + l31;
#pragma unroll
  for (int mt = 0; mt < 2; ++mt)
#pragma unroll
    for (int r = 0; r < 16; ++r) {
      int c = c0 + (wc * 2 + mt) * 32 + (r & 3) + 8 * (r >> 2) + 4 * h;
      float v = acc[mt][r] + ob[c];
      oc[((size_t)(b * C_ + c)) * HW_ + sp] = v;
      float vs = v, vs2 = v * v;
#pragma unroll
      for (int msk = 1; msk < 32; msk <<= 1) {
        vs += __shfl_xor(vs, msk, 64);
        vs2 += __shfl_xor(vs2, msk, 64);
      }
      if (l31 == 0) {
        atomicAdd(&bnsum[c], vs);
        atomicAdd(&bnsum[C_ + c], vs2);
      }
    }
}

// ---------------- K4: BN (training stats) + ReLU + residual ----------------
__global__ __launch_bounds__(256) void k4_final(
    const float* __restrict__ oc, const float* __restrict__ x,
    const float* __restrict__ bnsum, const float* __restrict__ gamma,
    const float* __restrict__ beta, float* __restrict__ out) {
  int gid = blockIdx.x * 256 + threadIdx.x;
  size_t base = (size_t)gid * 4;
  int c = (int)((base >> 12) & 255);
  float mean = bnsum[c] * (1.f / 16384.f);
  float var = bnsum[C_ + c] * (1.f / 16384.f) - mean * mean;
  float sc = gamma[c] * rsqrtf(var + 1e-5f);
  float bt = beta[c];
  f32x4 v = *(const f32x4*)&oc[base];
  f32x4 xv = *(const f32x4*)&x[base];
  f32x4 r;
#pragma unroll
  for (int j = 0; j < 4; ++j) {
    float y = (v[j] - mean) * sc + bt;
    y = fmaxf(y, 0.f);
    r[j] = y + xv[j];
  }
  *(f32x4*)&out[base] = r;
}

extern "C" void kernel_launch(void* const* d_in, const int* in_sizes, int n_in,
                              void* d_out, int out_size, void* d_ws,
                              size_t ws_size, hipStream_t stream) {
  const float* x = (const float*)d_in[0];
  const float* g_w = (const float*)d_in[1];
  const float* g_b = (const float*)d_in[2];
  const float* th_w = (const float*)d_in[3];
  const float* th_b = (const float*)d_in[4];
  const float* ph_w = (const float*)d_in[5];
  const float* ph_b = (const float*)d_in[6];
  const float* o_w = (const float*)d_in[7];
  const float* o_b = (const float*)d_in[8];
  const float* gam = (const float*)d_in[9];
  const float* bet = (const float*)d_in[10];

  char* ws = (char*)d_ws;
  _Float16* xP = (_Float16*)ws;                      // 8 MB
  _Float16* thetaP = (_Float16*)(ws + 8388608);      // 4 MB
  _Float16* phiP = (_Float16*)(ws + 12582912);       // 4 MB
  _Float16* gP = (_Float16*)(ws + 16777216);         // 4 MB
  _Float16* attnP = (_Float16*)(ws + 20971520);      // 4 MB
  _Float16* w16 = (_Float16*)(ws + 25165824);        // 256 KB
  float* ml = (float*)(ws + 25427968);               // 512 KB
  float* bn = (float*)(ws + 25952256);               // 2 KB
  _Float16* Opart = (_Float16*)d_out;  // 16 MB scratch, consumed before K3 writes oc
  float* oc = (float*)d_out;

  hipMemsetAsync(bn, 0, 2 * C_ * sizeof(float), stream);
  k0_transpose<<<dim3(64, 4, 4), 256, 0, stream>>>(x, xP);
  k0_wconv<<<64, 256, 0, stream>>>(th_w, ph_w, g_w, o_w, w16);
  k1_proj<<<dim3(64, 3, 4), 256, 0, stream>>>(xP, w16, th_b, ph_b, g_b, thetaP,
                                              phiP, gP);
  k2_attn<<<dim3(32, KS_, 4), 256, 0, stream>>>(thetaP, phiP, gP, Opart, ml);
  k2_merge<<<1024, 256, 0, stream>>>(Opart, ml, attnP);
  k3_outconv<<<dim3(64, 2, 4), 256, 0, stream>>>(attnP, w16 + 3 * 32768, o_b,
                                                 oc, bn);
  k4_final<<<4096, 256, 0, stream>>>(oc, x, bn, gam, bet, (float*)d_out);
}

// Round 5
// 214.545 us; speedup vs baseline: 1.6224x; 1.6224x over previous
//
#include <hip/hip_runtime.h>

#define B_ 4
#define C_ 256
#define CI_ 128
#define HW_ 4096
#define KS_ 4

typedef _Float16 f16x8 __attribute__((ext_vector_type(8)));
typedef _Float16 f16x4 __attribute__((ext_vector_type(4)));
typedef float f32x16 __attribute__((ext_vector_type(16)));
typedef float f32x4 __attribute__((ext_vector_type(4)));

__device__ __forceinline__ f32x16 mfma16(f16x8 a, f16x8 b, f32x16 c) {
  return __builtin_amdgcn_mfma_f32_32x32x16_f16(a, b, c, 0, 0, 0);
}
__device__ __forceinline__ f16x8 cat8(f16x4 a, f16x4 b) {
  return __builtin_shufflevector(a, b, 0, 1, 2, 3, 4, 5, 6, 7);
}

// Packed layouts (all MFMA operands):
//  16B granule: off16 = ((row>>5)*(K/8) + k8)*32 + (row&31); f16 idx = off16*8
//   8B granule: off8  = ((row>>5)*(K/4) + k4)*32 + (row&31); f16 idx = off8*4
// gP uses row=ci, k=key: off8 = (ciblk*(HW/4) + key4)*32 + (ci&31)

// ---------------- K0a: x (b,ch,sp) fp32 -> xP packed (row=sp, k=ch, 16B) ----------------
__global__ __launch_bounds__(256) void k0_transpose(const float* __restrict__ x,
                                                    _Float16* __restrict__ xP) {
  __shared__ _Float16 Lt[64 * 66];
  int t = threadIdx.x;
  int sp0 = blockIdx.x * 64;
  int ch0 = blockIdx.y * 64;
  int b = blockIdx.z;
  const float* xb = x + (size_t)b * C_ * HW_;
#pragma unroll
  for (int i = 0; i < 16; ++i) {
    int ch = i * 4 + (t >> 6);
    int sp = t & 63;
    Lt[ch * 66 + sp] = (_Float16)xb[(size_t)(ch0 + ch) * HW_ + sp0 + sp];
  }
  __syncthreads();
  _Float16* xPb = xP + (size_t)b * HW_ * C_;
  int l31 = t & 31;
  int c8 = t >> 5;  // 0..7
#pragma unroll
  for (int sph = 0; sph < 2; ++sph) {
    int spl = sph * 32 + l31;
    f16x8 v;
#pragma unroll
    for (int i = 0; i < 8; ++i) v[i] = Lt[(c8 * 8 + i) * 66 + spl];
    int sp = sp0 + spl;
    size_t off16 = ((size_t)(sp >> 5) * (C_ / 8) + (ch0 / 8 + c8)) * 32 + (sp & 31);
    *(f16x8*)&xPb[off16 * 8] = v;
  }
}

// ---------------- K0b: weights fp32 -> packed fp16 [theta|phi|g|out] ----------------
__global__ __launch_bounds__(256) void k0_wconv(const float* __restrict__ tw,
                                                const float* __restrict__ pw,
                                                const float* __restrict__ gw,
                                                const float* __restrict__ ow,
                                                _Float16* __restrict__ w16) {
  int g = blockIdx.x * 256 + threadIdx.x;  // 16384 chunks of 16B
  int ti = g >> 12;
  int local = g & 4095;
  const float* src = (ti == 0) ? tw : (ti == 1) ? pw : (ti == 2) ? gw : ow;
  int row, col;
  if (ti < 3) {  // 128 rows x 256 k
    int r31 = local & 31, k8 = (local >> 5) & 31, rblk = local >> 10;
    row = rblk * 32 + r31;
    col = k8 * 8;
    src += (size_t)row * 256 + col;
  } else {  // 256 rows x 128 k
    int r31 = local & 31, k8 = (local >> 5) & 15, rblk = local >> 9;
    row = rblk * 32 + r31;
    col = k8 * 8;
    src += (size_t)row * 128 + col;
  }
  f32x4 a = *(const f32x4*)src;
  f32x4 c = *(const f32x4*)(src + 4);
  f16x8 hv;
#pragma unroll
  for (int j = 0; j < 4; ++j) {
    hv[j] = (_Float16)a[j];
    hv[j + 4] = (_Float16)c[j];
  }
  *(f16x8*)&w16[(size_t)ti * 32768 + (size_t)local * 8] = hv;
}

// ---------------- K1: projections -> thetaP/phiP (row=q, k=ci, 8B), gP (row=ci, k=key, 8B) --
__global__ __launch_bounds__(256, 2) void k1_proj(
    const _Float16* __restrict__ xP, const _Float16* __restrict__ w16,
    const float* __restrict__ tb, const float* __restrict__ pb,
    const float* __restrict__ gb, _Float16* __restrict__ thetaP,
    _Float16* __restrict__ phiP, _Float16* __restrict__ gP) {
  int p = blockIdx.y;
  int b = blockIdx.z;
  int sp0 = blockIdx.x * 64;
  int tid = threadIdx.x;
  int w = tid >> 6;
  int lane = tid & 63;
  int l31 = lane & 31;
  int h = lane >> 5;
  const _Float16* xPb = xP + (size_t)b * HW_ * C_;
  f32x16 acc[2];
#pragma unroll
  for (int i = 0; i < 2; ++i)
#pragma unroll
    for (int j = 0; j < 16; ++j) acc[i][j] = 0.f;

  if (p < 2) {
    int wsp = w & 1, wci = w >> 1;
    const _Float16* W = w16 + (size_t)p * 32768;
#pragma unroll
    for (int ks = 0; ks < 16; ++ks) {
      int k8 = ks * 2 + h;
      f16x8 bf = *(const f16x8*)&xPb[((((sp0 >> 5) + wsp) * 32 + k8) * 32 + l31) * 8];
#pragma unroll
      for (int mt = 0; mt < 2; ++mt) {
        f16x8 af = *(const f16x8*)&W[((((wci * 2 + mt) * 32) + k8) * 32 + l31) * 8];
        acc[mt] = mfma16(af, bf, acc[mt]);
      }
    }
    const float* bias = (p == 0) ? tb : pb;
    _Float16* out = ((p == 0) ? thetaP : phiP) + (size_t)b * HW_ * CI_;
    int sp = sp0 + wsp * 32 + l31;
#pragma unroll
    for (int mt = 0; mt < 2; ++mt)
#pragma unroll
      for (int g4 = 0; g4 < 4; ++g4) {
        int cb = (wci * 2 + mt) * 32 + g4 * 8 + h * 4;
        f32x4 bv = *(const f32x4*)&bias[cb];
        f16x4 res;
#pragma unroll
        for (int j = 0; j < 4; ++j) res[j] = (_Float16)(acc[mt][g4 * 4 + j] + bv[j]);
        size_t off8 = ((size_t)(sp >> 5) * (CI_ / 4) + (cb >> 2)) * 32 + (sp & 31);
        *(f16x4*)&out[off8 * 4] = res;
      }
  } else {
    int wci = w;  // 0..3
    const _Float16* W = w16 + 2 * 32768;
#pragma unroll
    for (int ks = 0; ks < 16; ++ks) {
      int k8 = ks * 2 + h;
      f16x8 bf = *(const f16x8*)&W[((wci * 32 + k8) * 32 + l31) * 8];
#pragma unroll
      for (int mt = 0; mt < 2; ++mt) {
        f16x8 af = *(const f16x8*)&xPb[((((sp0 >> 5) + mt) * 32 + k8) * 32 + l31) * 8];
        acc[mt] = mfma16(af, bf, acc[mt]);
      }
    }
    float bv = gb[wci * 32 + l31];
    _Float16* out = gP + (size_t)b * CI_ * HW_;
#pragma unroll
    for (int mt = 0; mt < 2; ++mt)
#pragma unroll
      for (int g4 = 0; g4 < 4; ++g4) {
        int key4 = (sp0 >> 2) + mt * 8 + g4 * 2 + h;
        f16x4 res;
#pragma unroll
        for (int j = 0; j < 4; ++j) res[j] = (_Float16)(acc[mt][g4 * 4 + j] + bv);
        size_t off8 = ((size_t)wci * (HW_ / 4) + key4) * 32 + l31;
        *(f16x4*)&out[off8 * 4] = res;
      }
  }
}

// ---------------- K2: flash attention, 128q x 1024key per block, LDS-staged tiles -------
__global__ __launch_bounds__(256, 3) void k2_attn(
    const _Float16* __restrict__ thetaP, const _Float16* __restrict__ phiP,
    const _Float16* __restrict__ gP, _Float16* __restrict__ Opart,
    float* __restrict__ ml) {
  __shared__ _Float16 ldsPhi[8192];  // 16 KB: 64 keys x 128 ci, packed
  __shared__ _Float16 ldsG[8192];    // 16 KB: 128 ci x 64 keys, packed
  __shared__ _Float16 Pl[4 * 32 * 72];
  int s = blockIdx.y;
  int b = blockIdx.z;
  int q0 = blockIdx.x * 128;
  int tid = threadIdx.x;
  int w = tid >> 6;
  int lane = tid & 63;
  int l31 = lane & 31;
  int h = lane >> 5;
  int qblk = (q0 >> 5) + w;
  const _Float16* thb = thetaP + (size_t)b * HW_ * CI_;
  const _Float16* phb = phiP + (size_t)b * HW_ * CI_;
  const _Float16* gvb = gP + (size_t)b * CI_ * HW_;

  f16x8 Bq[8];
#pragma unroll
  for (int ks = 0; ks < 8; ++ks) {
    f16x4 lo = *(const f16x4*)&thb[(((size_t)qblk * 32 + ks * 4 + h * 2) * 32 + l31) * 4];
    f16x4 hi = *(const f16x4*)&thb[(((size_t)qblk * 32 + ks * 4 + h * 2 + 1) * 32 + l31) * 4];
    Bq[ks] = cat8(lo, hi);
  }

  f32x16 o[4];
#pragma unroll
  for (int i = 0; i < 4; ++i)
#pragma unroll
    for (int j = 0; j < 16; ++j) o[i][j] = 0.f;
  float m_run = -1e30f, l_run = 0.f;
  _Float16* Plw = &Pl[w * 32 * 72];

  for (int t = 0; t < 16; ++t) {  // 16 x 64 = 1024 keys per split
    int kb = s * 1024 + t * 64;
    // ---- stage phi (16KB) + g (16KB) tiles, coalesced linear copies ----
    {
      const _Float16* phiSrc = phb + (size_t)(kb >> 5) * 4096;  // f16 units
#pragma unroll
      for (int i = 0; i < 8; ++i) {
        int c = w * 8 + i;
        if (c < 16) {
          *(f16x8*)&ldsPhi[c * 512 + lane * 8] =
              *(const f16x8*)&phiSrc[c * 512 + lane * 8];
        } else {
          int j = c - 16;
          int seg = j >> 2, wi = j & 3;
          *(f16x8*)&ldsG[j * 512 + lane * 8] = *(const f16x8*)&gvb[
              ((size_t)seg * (HW_ / 4) + (kb >> 2)) * 128 + wi * 512 + lane * 8];
        }
      }
    }
    __syncthreads();
    // ---- QK^T (S^T): A = phi rows (key), B = theta (q) ----
    f32x16 sT[2];
#pragma unroll
    for (int i = 0; i < 2; ++i)
#pragma unroll
      for (int j = 0; j < 16; ++j) sT[i][j] = 0.f;
#pragma unroll
    for (int ks = 0; ks < 8; ++ks) {
#pragma unroll
      for (int mt = 0; mt < 2; ++mt) {
        const _Float16* pb2 = ldsPhi + mt * 4096;
        f16x4 lo = *(const f16x4*)&pb2[((ks * 4 + h * 2) * 32 + l31) * 4];
        f16x4 hi = *(const f16x4*)&pb2[((ks * 4 + h * 2 + 1) * 32 + l31) * 4];
        sT[mt] = mfma16(cat8(lo, hi), Bq[ks], sT[mt]);
      }
    }
    // ---- online softmax (per q = lane col; keys split across regs) ----
    float vmax = -1e30f;
#pragma unroll
    for (int mt = 0; mt < 2; ++mt)
#pragma unroll
      for (int r = 0; r < 16; ++r) vmax = fmaxf(vmax, sT[mt][r]);
    vmax = fmaxf(vmax, __shfl_xor(vmax, 32, 64));
    float m_new = fmaxf(m_run, vmax);
    float alpha = __expf(m_run - m_new);
    float psum = 0.f;
#pragma unroll
    for (int mt = 0; mt < 2; ++mt)
#pragma unroll
      for (int r = 0; r < 16; ++r) {
        float pv = __expf(sT[mt][r] - m_new);
        sT[mt][r] = pv;
        psum += pv;
      }
    psum += __shfl_xor(psum, 32, 64);
    l_run = l_run * alpha + psum;
    m_run = m_new;
#pragma unroll
    for (int i = 0; i < 4; ++i)
#pragma unroll
      for (int j = 0; j < 16; ++j) o[i][j] *= alpha;
    // ---- pack P^T into per-wave LDS [q][key] ----
#pragma unroll
    for (int mt = 0; mt < 2; ++mt)
#pragma unroll
      for (int g4 = 0; g4 < 4; ++g4) {
        f16x4 pk;
#pragma unroll
        for (int j = 0; j < 4; ++j) pk[j] = (_Float16)sT[mt][g4 * 4 + j];
        *(f16x4*)&Plw[l31 * 72 + mt * 32 + g4 * 8 + h * 4] = pk;
      }
    asm volatile("s_waitcnt lgkmcnt(0)" ::: "memory");
    // ---- PV: O^T += g (ci) x P^T (q) ----
#pragma unroll
    for (int kv = 0; kv < 4; ++kv) {
      f16x8 bp = *(const f16x8*)&Plw[l31 * 72 + kv * 16 + h * 8];
#pragma unroll
      for (int mt2 = 0; mt2 < 4; ++mt2) {
        const _Float16* gb2 = ldsG + mt2 * 2048;
        f16x4 lo = *(const f16x4*)&gb2[((kv * 4 + h * 2) * 32 + l31) * 4];
        f16x4 hi = *(const f16x4*)&gb2[((kv * 4 + h * 2 + 1) * 32 + l31) * 4];
        o[mt2] = mfma16(cat8(lo, hi), bp, o[mt2]);
      }
    }
    __syncthreads();
  }
  // ---- epilogue: normalized partial O in packed (row=q, k=ci, 8B) layout ----
  float inv = 1.f / l_run;
  int S = b * KS_ + s;
  size_t obase = (size_t)S * (HW_ * CI_ / 4);
#pragma unroll
  for (int mt2 = 0; mt2 < 4; ++mt2)
#pragma unroll
    for (int g4 = 0; g4 < 4; ++g4) {
      f16x4 res;
#pragma unroll
      for (int j = 0; j < 4; ++j) res[j] = (_Float16)(o[mt2][g4 * 4 + j] * inv);
      int ci4 = mt2 * 8 + g4 * 2 + h;
      size_t off8 = obase + ((size_t)qblk * 32 + ci4) * 32 + l31;
      *(f16x4*)&Opart[off8 * 4] = res;
    }
  if (h == 0) {
    int q = qblk * 32 + l31;
    *(float2*)&ml[((size_t)S * HW_ + q) * 2] = make_float2(m_run, l_run);
  }
}

// ---------------- K2m: merge KS_ splits -> attnP (row=q, k=ci, 16B) ----------------
__global__ __launch_bounds__(256) void k2_merge(const _Float16* __restrict__ Opart,
                                                const float* __restrict__ ml,
                                                _Float16* __restrict__ attnP) {
  int g = blockIdx.x * 256 + threadIdx.x;  // 2^18 chunks
  int q31 = g & 31;
  int ci8 = (g >> 5) & 15;
  int qblk = (g >> 9) & 127;
  int b = g >> 16;
  int q = qblk * 32 + q31;
  float m[KS_], l[KS_], M = -1e30f;
#pragma unroll
  for (int s = 0; s < KS_; ++s) {
    float2 v = *(const float2*)&ml[((size_t)(b * KS_ + s) * HW_ + q) * 2];
    m[s] = v.x;
    l[s] = v.y;
    M = fmaxf(M, m[s]);
  }
  float den = 0.f, wgt[KS_];
#pragma unroll
  for (int s = 0; s < KS_; ++s) {
    wgt[s] = __expf(m[s] - M) * l[s];
    den += wgt[s];
  }
  float inv = 1.f / den;
  f32x4 a0 = {0.f, 0.f, 0.f, 0.f}, a1 = {0.f, 0.f, 0.f, 0.f};
#pragma unroll
  for (int s = 0; s < KS_; ++s) {
    size_t base = (size_t)(b * KS_ + s) * (HW_ * CI_ / 4) +
                  ((size_t)qblk * 32 + ci8 * 2) * 32 + q31;
    f16x4 v0 = *(const f16x4*)&Opart[base * 4];
    f16x4 v1 = *(const f16x4*)&Opart[(base + 32) * 4];
#pragma unroll
    for (int j = 0; j < 4; ++j) {
      a0[j] += wgt[s] * (float)v0[j];
      a1[j] += wgt[s] * (float)v1[j];
    }
  }
  f16x8 res;
#pragma unroll
  for (int j = 0; j < 4; ++j) {
    res[j] = (_Float16)(a0[j] * inv);
    res[j + 4] = (_Float16)(a1[j] * inv);
  }
  size_t off16 = (size_t)b * (HW_ * CI_ / 8) + ((size_t)qblk * 16 + ci8) * 32 + q31;
  *(f16x8*)&attnP[off16 * 8] = res;
}

// ---------------- K3: out conv -> oc (no atomics) ----------------
__global__ __launch_bounds__(256, 2) void k3_outconv(
    const _Float16* __restrict__ attnP, const _Float16* __restrict__ wo,
    const float* __restrict__ ob, float* __restrict__ oc) {
  int b = blockIdx.z;
  int c0 = blockIdx.y * 128;
  int s0 = blockIdx.x * 64;
  int tid = threadIdx.x;
  int w = tid >> 6;
  int lane = tid & 63;
  int l31 = lane & 31;
  int h = lane >> 5;
  int wsp = w & 1, wc = w >> 1;
  const _Float16* ab = attnP + (size_t)b * HW_ * CI_;
  f32x16 acc[2];
#pragma unroll
  for (int i = 0; i < 2; ++i)
#pragma unroll
    for (int j = 0; j < 16; ++j) acc[i][j] = 0.f;
#pragma unroll
  for (int ks = 0; ks < 8; ++ks) {
    int k8 = ks * 2 + h;
    f16x8 bf = *(const f16x8*)&ab[((((s0 >> 5) + wsp) * 16 + k8) * 32 + l31) * 8];
#pragma unroll
    for (int mt = 0; mt < 2; ++mt) {
      int rblk = (c0 >> 5) + (wc * 2 + mt);
      f16x8 af = *(const f16x8*)&wo[((rblk * 16 + k8) * 32 + l31) * 8];
      acc[mt] = mfma16(af, bf, acc[mt]);
    }
  }
  int sp = s0 + wsp * 32 + l31;
#pragma unroll
  for (int mt = 0; mt < 2; ++mt)
#pragma unroll
    for (int r = 0; r < 16; ++r) {
      int c = c0 + (wc * 2 + mt) * 32 + (r & 3) + 8 * (r >> 2) + 4 * h;
      oc[((size_t)(b * C_ + c)) * HW_ + sp] = acc[mt][r] + ob[c];
    }
}

// ---------------- K3b: BN stats, one block per channel, no atomics ----------------
__global__ __launch_bounds__(256) void k3b_bnstats(const float* __restrict__ oc,
                                                   float* __restrict__ bnsum) {
  int c = blockIdx.x;
  int t = threadIdx.x;
  float s = 0.f, s2 = 0.f;
#pragma unroll
  for (int b = 0; b < B_; ++b) {
    const float* p = oc + ((size_t)(b * C_ + c)) * HW_;
    for (int i = t * 4; i < HW_; i += 1024) {
      f32x4 v = *(const f32x4*)&p[i];
#pragma unroll
      for (int j = 0; j < 4; ++j) {
        s += v[j];
        s2 += v[j] * v[j];
      }
    }
  }
#pragma unroll
  for (int m = 1; m < 64; m <<= 1) {
    s += __shfl_xor(s, m, 64);
    s2 += __shfl_xor(s2, m, 64);
  }
  __shared__ float ls[8];
  int w = t >> 6, lane = t & 63;
  if (lane == 0) {
    ls[w] = s;
    ls[4 + w] = s2;
  }
  __syncthreads();
  if (t == 0) {
    bnsum[c] = ls[0] + ls[1] + ls[2] + ls[3];
    bnsum[C_ + c] = ls[4] + ls[5] + ls[6] + ls[7];
  }
}

// ---------------- K4: BN (training stats) + ReLU + residual ----------------
__global__ __launch_bounds__(256) void k4_final(
    const float* __restrict__ oc, const float* __restrict__ x,
    const float* __restrict__ bnsum, const float* __restrict__ gamma,
    const float* __restrict__ beta, float* __restrict__ out) {
  int gid = blockIdx.x * 256 + threadIdx.x;
  size_t base = (size_t)gid * 4;
  int c = (int)((base >> 12) & 255);
  float mean = bnsum[c] * (1.f / 16384.f);
  float var = bnsum[C_ + c] * (1.f / 16384.f) - mean * mean;
  float sc = gamma[c] * rsqrtf(var + 1e-5f);
  float bt = beta[c];
  f32x4 v = *(const f32x4*)&oc[base];
  f32x4 xv = *(const f32x4*)&x[base];
  f32x4 r;
#pragma unroll
  for (int j = 0; j < 4; ++j) {
    float y = (v[j] - mean) * sc + bt;
    y = fmaxf(y, 0.f);
    r[j] = y + xv[j];
  }
  *(f32x4*)&out[base] = r;
}

extern "C" void kernel_launch(void* const* d_in, const int* in_sizes, int n_in,
                              void* d_out, int out_size, void* d_ws,
                              size_t ws_size, hipStream_t stream) {
  const float* x = (const float*)d_in[0];
  const float* g_w = (const float*)d_in[1];
  const float* g_b = (const float*)d_in[2];
  const float* th_w = (const float*)d_in[3];
  const float* th_b = (const float*)d_in[4];
  const float* ph_w = (const float*)d_in[5];
  const float* ph_b = (const float*)d_in[6];
  const float* o_w = (const float*)d_in[7];
  const float* o_b = (const float*)d_in[8];
  const float* gam = (const float*)d_in[9];
  const float* bet = (const float*)d_in[10];

  char* ws = (char*)d_ws;
  _Float16* xP = (_Float16*)ws;                      // 8 MB
  _Float16* thetaP = (_Float16*)(ws + 8388608);      // 4 MB
  _Float16* phiP = (_Float16*)(ws + 12582912);       // 4 MB
  _Float16* gP = (_Float16*)(ws + 16777216);         // 4 MB
  _Float16* attnP = (_Float16*)(ws + 20971520);      // 4 MB
  _Float16* w16 = (_Float16*)(ws + 25165824);        // 256 KB
  float* ml = (float*)(ws + 25427968);               // 512 KB
  float* bn = (float*)(ws + 25952256);               // 2 KB
  _Float16* Opart = (_Float16*)d_out;  // 16 MB scratch, consumed before K3 writes oc
  float* oc = (float*)d_out;

  k0_transpose<<<dim3(64, 4, 4), 256, 0, stream>>>(x, xP);
  k0_wconv<<<64, 256, 0, stream>>>(th_w, ph_w, g_w, o_w, w16);
  k1_proj<<<dim3(64, 3, 4), 256, 0, stream>>>(xP, w16, th_b, ph_b, g_b, thetaP,
                                              phiP, gP);
  k2_attn<<<dim3(32, KS_, 4), 256, 0, stream>>>(thetaP, phiP, gP, Opart, ml);
  k2_merge<<<1024, 256, 0, stream>>>(Opart, ml, attnP);
  k3_outconv<<<dim3(64, 2, 4), 256, 0, stream>>>(attnP, w16 + 3 * 32768, o_b, oc);
  k3b_bnstats<<<256, 256, 0, stream>>>(oc, bn);
  k4_final<<<4096, 256, 0, stream>>>(oc, x, bn, gam, bet, (float*)d_out);
}

// Round 7
// 176.618 us; speedup vs baseline: 1.9708x; 1.2147x over previous
//
#include <hip/hip_runtime.h>

#define B_ 4
#define C_ 256
#define CI_ 128
#define HW_ 4096
#define KS_ 4
#define LOG2E 1.44269504f

typedef _Float16 f16x8 __attribute__((ext_vector_type(8)));
typedef _Float16 f16x4 __attribute__((ext_vector_type(4)));
typedef float f32x16 __attribute__((ext_vector_type(16)));
typedef float f32x4 __attribute__((ext_vector_type(4)));

__device__ __forceinline__ f32x16 mfma16(f16x8 a, f16x8 b, f32x16 c) {
  return __builtin_amdgcn_mfma_f32_32x32x16_f16(a, b, c, 0, 0, 0);
}
__device__ __forceinline__ f16x8 cat8(f16x4 a, f16x4 b) {
  return __builtin_shufflevector(a, b, 0, 1, 2, 3, 4, 5, 6, 7);
}
union QW { f16x4 v; long long q; };

// Packed layouts (all MFMA operands):
//  16B granule: off16 = ((row>>5)*(K/8) + k8)*32 + (row&31); f16 idx = off16*8
//   8B granule: off8  = ((row>>5)*(K/4) + k4)*32 + (row&31); f16 idx = off8*4
// gP uses row=ci, k=key: off8 = (ciblk*(HW/4) + key4)*32 + (ci&31)

// ---------------- K0a: x (b,ch,sp) fp32 -> xP packed (row=sp, k=ch, 16B) ----------------
__global__ __launch_bounds__(256) void k0_transpose(const float* __restrict__ x,
                                                    _Float16* __restrict__ xP) {
  __shared__ _Float16 Lt[64 * 66];
  int t = threadIdx.x;
  int sp0 = blockIdx.x * 64;
  int ch0 = blockIdx.y * 64;
  int b = blockIdx.z;
  const float* xb = x + (size_t)b * C_ * HW_;
#pragma unroll
  for (int i = 0; i < 16; ++i) {
    int ch = i * 4 + (t >> 6);
    int sp = t & 63;
    Lt[ch * 66 + sp] = (_Float16)xb[(size_t)(ch0 + ch) * HW_ + sp0 + sp];
  }
  __syncthreads();
  _Float16* xPb = xP + (size_t)b * HW_ * C_;
  int l31 = t & 31;
  int c8 = t >> 5;  // 0..7
#pragma unroll
  for (int sph = 0; sph < 2; ++sph) {
    int spl = sph * 32 + l31;
    f16x8 v;
#pragma unroll
    for (int i = 0; i < 8; ++i) v[i] = Lt[(c8 * 8 + i) * 66 + spl];
    int sp = sp0 + spl;
    size_t off16 = ((size_t)(sp >> 5) * (C_ / 8) + (ch0 / 8 + c8)) * 32 + (sp & 31);
    *(f16x8*)&xPb[off16 * 8] = v;
  }
}

// ---------------- K0b: weights fp32 -> packed fp16 [theta|phi|g|out]; theta *= log2e ----
__global__ __launch_bounds__(256) void k0_wconv(const float* __restrict__ tw,
                                                const float* __restrict__ pw,
                                                const float* __restrict__ gw,
                                                const float* __restrict__ ow,
                                                _Float16* __restrict__ w16) {
  int g = blockIdx.x * 256 + threadIdx.x;  // 16384 chunks of 16B
  int ti = g >> 12;
  int local = g & 4095;
  const float* src = (ti == 0) ? tw : (ti == 1) ? pw : (ti == 2) ? gw : ow;
  float scl = (ti == 0) ? LOG2E : 1.f;
  int row, col;
  if (ti < 3) {  // 128 rows x 256 k
    int r31 = local & 31, k8 = (local >> 5) & 31, rblk = local >> 10;
    row = rblk * 32 + r31;
    col = k8 * 8;
    src += (size_t)row * 256 + col;
  } else {  // 256 rows x 128 k
    int r31 = local & 31, k8 = (local >> 5) & 15, rblk = local >> 9;
    row = rblk * 32 + r31;
    col = k8 * 8;
    src += (size_t)row * 128 + col;
  }
  f32x4 a = *(const f32x4*)src;
  f32x4 c = *(const f32x4*)(src + 4);
  f16x8 hv;
#pragma unroll
  for (int j = 0; j < 4; ++j) {
    hv[j] = (_Float16)(a[j] * scl);
    hv[j + 4] = (_Float16)(c[j] * scl);
  }
  *(f16x8*)&w16[(size_t)ti * 32768 + (size_t)local * 8] = hv;
}

// ---------------- K1: projections -> thetaP/phiP (row=q, k=ci, 8B), gP (row=ci, k=key, 8B) --
__global__ __launch_bounds__(256, 2) void k1_proj(
    const _Float16* __restrict__ xP, const _Float16* __restrict__ w16,
    const float* __restrict__ tb, const float* __restrict__ pb,
    const float* __restrict__ gb, _Float16* __restrict__ thetaP,
    _Float16* __restrict__ phiP, _Float16* __restrict__ gP) {
  int p = blockIdx.y;
  int b = blockIdx.z;
  int sp0 = blockIdx.x * 64;
  int tid = threadIdx.x;
  int w = tid >> 6;
  int lane = tid & 63;
  int l31 = lane & 31;
  int h = lane >> 5;
  const _Float16* xPb = xP + (size_t)b * HW_ * C_;
  f32x16 acc[2];
#pragma unroll
  for (int i = 0; i < 2; ++i)
#pragma unroll
    for (int j = 0; j < 16; ++j) acc[i][j] = 0.f;

  if (p < 2) {
    int wsp = w & 1, wci = w >> 1;
    const _Float16* W = w16 + (size_t)p * 32768;
#pragma unroll
    for (int ks = 0; ks < 16; ++ks) {
      int k8 = ks * 2 + h;
      f16x8 bf = *(const f16x8*)&xPb[((((sp0 >> 5) + wsp) * 32 + k8) * 32 + l31) * 8];
#pragma unroll
      for (int mt = 0; mt < 2; ++mt) {
        f16x8 af = *(const f16x8*)&W[((((wci * 2 + mt) * 32) + k8) * 32 + l31) * 8];
        acc[mt] = mfma16(af, bf, acc[mt]);
      }
    }
    const float* bias = (p == 0) ? tb : pb;
    float bscl = (p == 0) ? LOG2E : 1.f;
    _Float16* out = ((p == 0) ? thetaP : phiP) + (size_t)b * HW_ * CI_;
    int sp = sp0 + wsp * 32 + l31;
#pragma unroll
    for (int mt = 0; mt < 2; ++mt)
#pragma unroll
      for (int g4 = 0; g4 < 4; ++g4) {
        int cb = (wci * 2 + mt) * 32 + g4 * 8 + h * 4;
        f32x4 bv = *(const f32x4*)&bias[cb];
        f16x4 res;
#pragma unroll
        for (int j = 0; j < 4; ++j)
          res[j] = (_Float16)(acc[mt][g4 * 4 + j] + bv[j] * bscl);
        size_t off8 = ((size_t)(sp >> 5) * (CI_ / 4) + (cb >> 2)) * 32 + (sp & 31);
        *(f16x4*)&out[off8 * 4] = res;
      }
  } else {
    int wci = w;  // 0..3
    const _Float16* W = w16 + 2 * 32768;
#pragma unroll
    for (int ks = 0; ks < 16; ++ks) {
      int k8 = ks * 2 + h;
      f16x8 bf = *(const f16x8*)&W[((wci * 32 + k8) * 32 + l31) * 8];
#pragma unroll
      for (int mt = 0; mt < 2; ++mt) {
        f16x8 af = *(const f16x8*)&xPb[((((sp0 >> 5) + mt) * 32 + k8) * 32 + l31) * 8];
        acc[mt] = mfma16(af, bf, acc[mt]);
      }
    }
    float bv = gb[wci * 32 + l31];
    _Float16* out = gP + (size_t)b * CI_ * HW_;
#pragma unroll
    for (int mt = 0; mt < 2; ++mt)
#pragma unroll
      for (int g4 = 0; g4 < 4; ++g4) {
        int key4 = (sp0 >> 2) + mt * 8 + g4 * 2 + h;
        f16x4 res;
#pragma unroll
        for (int j = 0; j < 4; ++j) res[j] = (_Float16)(acc[mt][g4 * 4 + j] + bv);
        size_t off8 = ((size_t)wci * (HW_ / 4) + key4) * 32 + l31;
        *(f16x4*)&out[off8 * 4] = res;
      }
  }
}

// ---------------- K2: flash attention, reg-prefetch pipeline, shuffle P-exchange --------
__global__ __launch_bounds__(256, 2) void k2_attn(
    const _Float16* __restrict__ thetaP, const _Float16* __restrict__ phiP,
    const _Float16* __restrict__ gP, _Float16* __restrict__ Opart,
    float* __restrict__ ml) {
  __shared__ _Float16 ldsPhi[8192];  // 16 KB: 64 keys x 128 ci, packed
  __shared__ _Float16 ldsG[8192];    // 16 KB: 128 ci x 64 keys, packed
  int s = blockIdx.y;
  int b = blockIdx.z;
  int q0 = blockIdx.x * 128;
  int tid = threadIdx.x;
  int w = tid >> 6;
  int lane = tid & 63;
  int l31 = lane & 31;
  int h = lane >> 5;
  int qblk = (q0 >> 5) + w;
  const _Float16* thb = thetaP + (size_t)b * HW_ * CI_;
  const _Float16* phb = phiP + (size_t)b * HW_ * CI_;
  const _Float16* gvb = gP + (size_t)b * CI_ * HW_;

  f16x8 Bq[8];
#pragma unroll
  for (int ks = 0; ks < 8; ++ks) {
    f16x4 lo = *(const f16x4*)&thb[(((size_t)qblk * 32 + ks * 4 + h * 2) * 32 + l31) * 4];
    f16x4 hi = *(const f16x4*)&thb[(((size_t)qblk * 32 + ks * 4 + h * 2 + 1) * 32 + l31) * 4];
    Bq[ks] = cat8(lo, hi);
  }

  f32x16 o[4];
#pragma unroll
  for (int i = 0; i < 4; ++i)
#pragma unroll
    for (int j = 0; j < 16; ++j) o[i][j] = 0.f;
  float m_run = -1e30f, l_run = 0.f;

  f16x8 pf[8];
  auto load_pf = [&](int kb) {
    const _Float16* phiSrc = phb + (size_t)(kb >> 5) * 4096;
#pragma unroll
    for (int i = 0; i < 8; ++i) {
      int cc = w * 8 + i;
      if (cc < 16) {
        pf[i] = *(const f16x8*)&phiSrc[cc * 512 + lane * 8];
      } else {
        int j = cc - 16, seg = j >> 2, wi = j & 3;
        pf[i] = *(const f16x8*)&gvb[((size_t)seg * (HW_ / 4) + (kb >> 2)) * 128 +
                                    wi * 512 + lane * 8];
      }
    }
  };

  load_pf(s * 1024);

  for (int t = 0; t < 16; ++t) {
    // ---- commit prefetched tile to LDS ----
#pragma unroll
    for (int i = 0; i < 8; ++i) {
      int cc = w * 8 + i;
      if (cc < 16)
        *(f16x8*)&ldsPhi[cc * 512 + lane * 8] = pf[i];
      else
        *(f16x8*)&ldsG[(cc - 16) * 512 + lane * 8] = pf[i];
    }
    __syncthreads();
    // ---- issue next tile's global loads (latency hidden behind compute) ----
    if (t < 15) load_pf(s * 1024 + (t + 1) * 64);
    // ---- QK^T (S^T): A = phi rows (key), B = theta (q) ----
    f32x16 sT[2];
#pragma unroll
    for (int i = 0; i < 2; ++i)
#pragma unroll
      for (int j = 0; j < 16; ++j) sT[i][j] = 0.f;
#pragma unroll
    for (int ks = 0; ks < 8; ++ks) {
#pragma unroll
      for (int mt = 0; mt < 2; ++mt) {
        const _Float16* pb2 = ldsPhi + mt * 4096;
        f16x4 lo = *(const f16x4*)&pb2[((ks * 4 + h * 2) * 32 + l31) * 4];
        f16x4 hi = *(const f16x4*)&pb2[((ks * 4 + h * 2 + 1) * 32 + l31) * 4];
        sT[mt] = mfma16(cat8(lo, hi), Bq[ks], sT[mt]);
      }
    }
    // ---- online softmax, log2 domain (theta pre-scaled by log2e) ----
    float vmax = -1e30f;
#pragma unroll
    for (int mt = 0; mt < 2; ++mt)
#pragma unroll
      for (int r = 0; r < 16; ++r) vmax = fmaxf(vmax, sT[mt][r]);
    vmax = fmaxf(vmax, __shfl_xor(vmax, 32, 64));
    float m_new = fmaxf(m_run, vmax);
    float alpha = exp2f(m_run - m_new);
    float psum = 0.f;
#pragma unroll
    for (int mt = 0; mt < 2; ++mt)
#pragma unroll
      for (int r = 0; r < 16; ++r) {
        float pv = exp2f(sT[mt][r] - m_new);
        sT[mt][r] = pv;
        psum += pv;
      }
    psum += __shfl_xor(psum, 32, 64);
    l_run = l_run * alpha + psum;
    m_run = m_new;
#pragma unroll
    for (int i = 0; i < 4; ++i)
#pragma unroll
      for (int j = 0; j < 16; ++j) o[i][j] *= alpha;
    // ---- P: C-layout -> B-operand via cross-half shuffle (no LDS) ----
    // lane(h) holds offsets {a*8 + 4h + j}; B-frag needs {8h + 0..7}.
    f16x8 pfrag[4];
#pragma unroll
    for (int mt = 0; mt < 2; ++mt)
#pragma unroll
      for (int k2i = 0; k2i < 2; ++k2i) {
        int rb = k2i * 8;
        f16x4 A0, A1;
#pragma unroll
        for (int j = 0; j < 4; ++j) {
          A0[j] = (_Float16)sT[mt][rb + j];      // offsets 4h + j
          A1[j] = (_Float16)sT[mt][rb + 4 + j];  // offsets 8 + 4h + j
        }
        QW snd;
        snd.v = h ? A0 : A1;  // h=0 sends 8..11, h=1 sends 4..7
        QW rcv;
        rcv.q = __shfl_xor(snd.q, 32, 64);
        pfrag[mt * 2 + k2i] = h ? cat8(rcv.v, A1) : cat8(A0, rcv.v);
      }
    // ---- PV: O^T += g (ci) x P^T (q) ----
#pragma unroll
    for (int kv = 0; kv < 4; ++kv) {
#pragma unroll
      for (int mt2 = 0; mt2 < 4; ++mt2) {
        const _Float16* gb2 = ldsG + mt2 * 2048;
        f16x4 lo = *(const f16x4*)&gb2[((kv * 4 + h * 2) * 32 + l31) * 4];
        f16x4 hi = *(const f16x4*)&gb2[((kv * 4 + h * 2 + 1) * 32 + l31) * 4];
        o[mt2] = mfma16(cat8(lo, hi), pfrag[kv], o[mt2]);
      }
    }
    __syncthreads();
  }
  // ---- epilogue: normalized partial O in packed (row=q, k=ci, 8B) layout ----
  float inv = 1.f / l_run;
  int S = b * KS_ + s;
  size_t obase = (size_t)S * (HW_ * CI_ / 4);
#pragma unroll
  for (int mt2 = 0; mt2 < 4; ++mt2)
#pragma unroll
    for (int g4 = 0; g4 < 4; ++g4) {
      f16x4 res;
#pragma unroll
      for (int j = 0; j < 4; ++j) res[j] = (_Float16)(o[mt2][g4 * 4 + j] * inv);
      int ci4 = mt2 * 8 + g4 * 2 + h;
      size_t off8 = obase + ((size_t)qblk * 32 + ci4) * 32 + l31;
      *(f16x4*)&Opart[off8 * 4] = res;
    }
  if (h == 0) {
    int q = qblk * 32 + l31;
    *(float2*)&ml[((size_t)S * HW_ + q) * 2] = make_float2(m_run, l_run);
  }
}

// ---------------- K2m: merge KS_ splits -> attnP (row=q, k=ci, 16B) ----------------
__global__ __launch_bounds__(256) void k2_merge(const _Float16* __restrict__ Opart,
                                                const float* __restrict__ ml,
                                                _Float16* __restrict__ attnP) {
  int g = blockIdx.x * 256 + threadIdx.x;  // 2^18 chunks
  int q31 = g & 31;
  int ci8 = (g >> 5) & 15;
  int qblk = (g >> 9) & 127;
  int b = g >> 16;
  int q = qblk * 32 + q31;
  float m[KS_], l[KS_], M = -1e30f;
#pragma unroll
  for (int s = 0; s < KS_; ++s) {
    float2 v = *(const float2*)&ml[((size_t)(b * KS_ + s) * HW_ + q) * 2];
    m[s] = v.x;
    l[s] = v.y;
    M = fmaxf(M, m[s]);
  }
  float den = 0.f, wgt[KS_];
#pragma unroll
  for (int s = 0; s < KS_; ++s) {
    wgt[s] = exp2f(m[s] - M) * l[s];
    den += wgt[s];
  }
  float inv = 1.f / den;
  f32x4 a0 = {0.f, 0.f, 0.f, 0.f}, a1 = {0.f, 0.f, 0.f, 0.f};
#pragma unroll
  for (int s = 0; s < KS_; ++s) {
    size_t base = (size_t)(b * KS_ + s) * (HW_ * CI_ / 4) +
                  ((size_t)qblk * 32 + ci8 * 2) * 32 + q31;
    f16x4 v0 = *(const f16x4*)&Opart[base * 4];
    f16x4 v1 = *(const f16x4*)&Opart[(base + 32) * 4];
#pragma unroll
    for (int j = 0; j < 4; ++j) {
      a0[j] += wgt[s] * (float)v0[j];
      a1[j] += wgt[s] * (float)v1[j];
    }
  }
  f16x8 res;
#pragma unroll
  for (int j = 0; j < 4; ++j) {
    res[j] = (_Float16)(a0[j] * inv);
    res[j + 4] = (_Float16)(a1[j] * inv);
  }
  size_t off16 = (size_t)b * (HW_ * CI_ / 8) + ((size_t)qblk * 16 + ci8) * 32 + q31;
  *(f16x8*)&attnP[off16 * 8] = res;
}

// ---------------- K3: out conv -> oc (no atomics) ----------------
__global__ __launch_bounds__(256, 2) void k3_outconv(
    const _Float16* __restrict__ attnP, const _Float16* __restrict__ wo,
    const float* __restrict__ ob, float* __restrict__ oc) {
  int b = blockIdx.z;
  int c0 = blockIdx.y * 128;
  int s0 = blockIdx.x * 64;
  int tid = threadIdx.x;
  int w = tid >> 6;
  int lane = tid & 63;
  int l31 = lane & 31;
  int h = lane >> 5;
  int wsp = w & 1, wc = w >> 1;
  const _Float16* ab = attnP + (size_t)b * HW_ * CI_;
  f32x16 acc[2];
#pragma unroll
  for (int i = 0; i < 2; ++i)
#pragma unroll
    for (int j = 0; j < 16; ++j) acc[i][j] = 0.f;
#pragma unroll
  for (int ks = 0; ks < 8; ++ks) {
    int k8 = ks * 2 + h;
    f16x8 bf = *(const f16x8*)&ab[((((s0 >> 5) + wsp) * 16 + k8) * 32 + l31) * 8];
#pragma unroll
    for (int mt = 0; mt < 2; ++mt) {
      int rblk = (c0 >> 5) + (wc * 2 + mt);
      f16x8 af = *(const f16x8*)&wo[((rblk * 16 + k8) * 32 + l31) * 8];
      acc[mt] = mfma16(af, bf, acc[mt]);
    }
  }
  int sp = s0 + wsp * 32 + l31;
#pragma unroll
  for (int mt = 0; mt < 2; ++mt)
#pragma unroll
    for (int r = 0; r < 16; ++r) {
      int c = c0 + (wc * 2 + mt) * 32 + (r & 3) + 8 * (r >> 2) + 4 * h;
      oc[((size_t)(b * C_ + c)) * HW_ + sp] = acc[mt][r] + ob[c];
    }
}

// ---------------- K3b: BN stats, one block per channel, no atomics ----------------
__global__ __launch_bounds__(256) void k3b_bnstats(const float* __restrict__ oc,
                                                   float* __restrict__ bnsum) {
  int c = blockIdx.x;
  int t = threadIdx.x;
  float s = 0.f, s2 = 0.f;
#pragma unroll
  for (int b = 0; b < B_; ++b) {
    const float* p = oc + ((size_t)(b * C_ + c)) * HW_;
    for (int i = t * 4; i < HW_; i += 1024) {
      f32x4 v = *(const f32x4*)&p[i];
#pragma unroll
      for (int j = 0; j < 4; ++j) {
        s += v[j];
        s2 += v[j] * v[j];
      }
    }
  }
#pragma unroll
  for (int m = 1; m < 64; m <<= 1) {
    s += __shfl_xor(s, m, 64);
    s2 += __shfl_xor(s2, m, 64);
  }
  __shared__ float ls[8];
  int w = t >> 6, lane = t & 63;
  if (lane == 0) {
    ls[w] = s;
    ls[4 + w] = s2;
  }
  __syncthreads();
  if (t == 0) {
    bnsum[c] = ls[0] + ls[1] + ls[2] + ls[3];
    bnsum[C_ + c] = ls[4] + ls[5] + ls[6] + ls[7];
  }
}

// ---------------- K4: BN (training stats) + ReLU + residual ----------------
__global__ __launch_bounds__(256) void k4_final(
    const float* __restrict__ oc, const float* __restrict__ x,
    const float* __restrict__ bnsum, const float* __restrict__ gamma,
    const float* __restrict__ beta, float* __restrict__ out) {
  int gid = blockIdx.x * 256 + threadIdx.x;
  size_t base = (size_t)gid * 4;
  int c = (int)((base >> 12) & 255);
  float mean = bnsum[c] * (1.f / 16384.f);
  float var = bnsum[C_ + c] * (1.f / 16384.f) - mean * mean;
  float sc = gamma[c] * rsqrtf(var + 1e-5f);
  float bt = beta[c];
  f32x4 v = *(const f32x4*)&oc[base];
  f32x4 xv = *(const f32x4*)&x[base];
  f32x4 r;
#pragma unroll
  for (int j = 0; j < 4; ++j) {
    float y = (v[j] - mean) * sc + bt;
    y = fmaxf(y, 0.f);
    r[j] = y + xv[j];
  }
  *(f32x4*)&out[base] = r;
}

extern "C" void kernel_launch(void* const* d_in, const int* in_sizes, int n_in,
                              void* d_out, int out_size, void* d_ws,
                              size_t ws_size, hipStream_t stream) {
  const float* x = (const float*)d_in[0];
  const float* g_w = (const float*)d_in[1];
  const float* g_b = (const float*)d_in[2];
  const float* th_w = (const float*)d_in[3];
  const float* th_b = (const float*)d_in[4];
  const float* ph_w = (const float*)d_in[5];
  const float* ph_b = (const float*)d_in[6];
  const float* o_w = (const float*)d_in[7];
  const float* o_b = (const float*)d_in[8];
  const float* gam = (const float*)d_in[9];
  const float* bet = (const float*)d_in[10];

  char* ws = (char*)d_ws;
  _Float16* xP = (_Float16*)ws;                      // 8 MB
  _Float16* thetaP = (_Float16*)(ws + 8388608);      // 4 MB
  _Float16* phiP = (_Float16*)(ws + 12582912);       // 4 MB
  _Float16* gP = (_Float16*)(ws + 16777216);         // 4 MB
  _Float16* attnP = (_Float16*)(ws + 20971520);      // 4 MB
  _Float16* w16 = (_Float16*)(ws + 25165824);        // 256 KB
  float* ml = (float*)(ws + 25427968);               // 512 KB
  float* bn = (float*)(ws + 25952256);               // 2 KB
  _Float16* Opart = (_Float16*)d_out;  // 16 MB scratch, consumed before K3 writes oc
  float* oc = (float*)d_out;

  k0_transpose<<<dim3(64, 4, 4), 256, 0, stream>>>(x, xP);
  k0_wconv<<<64, 256, 0, stream>>>(th_w, ph_w, g_w, o_w, w16);
  k1_proj<<<dim3(64, 3, 4), 256, 0, stream>>>(xP, w16, th_b, ph_b, g_b, thetaP,
                                              phiP, gP);
  k2_attn<<<dim3(32, KS_, 4), 256, 0, stream>>>(thetaP, phiP, gP, Opart, ml);
  k2_merge<<<1024, 256, 0, stream>>>(Opart, ml, attnP);
  k3_outconv<<<dim3(64, 2, 4), 256, 0, stream>>>(attnP, w16 + 3 * 32768, o_b, oc);
  k3b_bnstats<<<256, 256, 0, stream>>>(oc, bn);
  k4_final<<<4096, 256, 0, stream>>>(oc, x, bn, gam, bet, (float*)d_out);
}

// Round 11
// 165.148 us; speedup vs baseline: 2.1077x; 1.0694x over previous
//
#include <hip/hip_runtime.h>

#define B_ 4
#define C_ 256
#define CI_ 128
#define HW_ 4096
#define KS_ 4
#define LOG2E 1.44269504f

typedef _Float16 f16x8 __attribute__((ext_vector_type(8)));
typedef _Float16 f16x4 __attribute__((ext_vector_type(4)));
typedef _Float16 f16x2 __attribute__((ext_vector_type(2)));
typedef __fp16 fp16x2 __attribute__((ext_vector_type(2)));
typedef float f32x16 __attribute__((ext_vector_type(16)));
typedef float f32x4 __attribute__((ext_vector_type(4)));

__device__ __forceinline__ f32x16 mfma16(f16x8 a, f16x8 b, f32x16 c) {
  return __builtin_amdgcn_mfma_f32_32x32x16_f16(a, b, c, 0, 0, 0);
}
__device__ __forceinline__ f16x8 cat8(f16x4 a, f16x4 b) {
  return __builtin_shufflevector(a, b, 0, 1, 2, 3, 4, 5, 6, 7);
}
__device__ __forceinline__ f16x4 pk4(float a, float b, float c, float d) {
  union { fp16x2 p[2]; f16x4 v; } u;
  u.p[0] = __builtin_amdgcn_cvt_pkrtz(a, b);
  u.p[1] = __builtin_amdgcn_cvt_pkrtz(c, d);
  return u.v;
}
union QW { f16x4 v; long long q; };
union F4 { f16x4 v; f16x2 h2[2]; };

// Packed layouts (all MFMA operands):
//  16B granule: off16 = ((row>>5)*(K/8) + k8)*32 + (row&31); f16 idx = off16*8
//   8B granule: off8  = ((row>>5)*(K/4) + k4)*32 + (row&31); f16 idx = off8*4
// gP uses row=ci, k=key: off8 = (ciblk*(HW/4) + key4)*32 + (ci&31)

// ---------------- K0: x transpose -> xP packed  (+ 64 blocks also pack weights) --------
__global__ __launch_bounds__(256) void k0_prep(
    const float* __restrict__ x, _Float16* __restrict__ xP,
    const float* __restrict__ tw, const float* __restrict__ pw,
    const float* __restrict__ gw, const float* __restrict__ ow,
    _Float16* __restrict__ w16) {
  __shared__ _Float16 Lt[64 * 66];
  int t = threadIdx.x;
  int sp0 = blockIdx.x * 64;
  int ch0 = blockIdx.y * 64;
  int b = blockIdx.z;
  const float* xb = x + (size_t)b * C_ * HW_;
#pragma unroll
  for (int i = 0; i < 16; ++i) {
    int ch = i * 4 + (t >> 6);
    int sp = t & 63;
    Lt[ch * 66 + sp] = (_Float16)xb[(size_t)(ch0 + ch) * HW_ + sp0 + sp];
  }
  __syncthreads();
  _Float16* xPb = xP + (size_t)b * HW_ * C_;
  int l31 = t & 31;
  int c8 = t >> 5;  // 0..7
#pragma unroll
  for (int sph = 0; sph < 2; ++sph) {
    int spl = sph * 32 + l31;
    f16x8 v;
#pragma unroll
    for (int i = 0; i < 8; ++i) v[i] = Lt[(c8 * 8 + i) * 66 + spl];
    int sp = sp0 + spl;
    size_t off16 = ((size_t)(sp >> 5) * (C_ / 8) + (ch0 / 8 + c8)) * 32 + (sp & 31);
    *(f16x8*)&xPb[off16 * 8] = v;
  }
  // weight packing piggyback on 64 blocks (theta scaled by log2e)
  if (blockIdx.y == 0 && blockIdx.z == 0) {
    int g = blockIdx.x * 256 + t;  // 16384 chunks of 16B
    int ti = g >> 12;
    int local = g & 4095;
    const float* src = (ti == 0) ? tw : (ti == 1) ? pw : (ti == 2) ? gw : ow;
    float scl = (ti == 0) ? LOG2E : 1.f;
    if (ti < 3) {
      int r31 = local & 31, k8 = (local >> 5) & 31, rblk = local >> 10;
      src += (size_t)(rblk * 32 + r31) * 256 + k8 * 8;
    } else {
      int r31 = local & 31, k8 = (local >> 5) & 15, rblk = local >> 9;
      src += (size_t)(rblk * 32 + r31) * 128 + k8 * 8;
    }
    f32x4 a = *(const f32x4*)src;
    f32x4 c = *(const f32x4*)(src + 4);
    f16x8 hv;
#pragma unroll
    for (int j = 0; j < 4; ++j) {
      hv[j] = (_Float16)(a[j] * scl);
      hv[j + 4] = (_Float16)(c[j] * scl);
    }
    *(f16x8*)&w16[(size_t)ti * 32768 + (size_t)local * 8] = hv;
  }
}

// ---------------- K1: projections -> thetaP/phiP (row=q, k=ci, 8B), gP (row=ci, k=key, 8B) --
__global__ __launch_bounds__(256, 2) void k1_proj(
    const _Float16* __restrict__ xP, const _Float16* __restrict__ w16,
    const float* __restrict__ tb, const float* __restrict__ pb,
    const float* __restrict__ gb, _Float16* __restrict__ thetaP,
    _Float16* __restrict__ phiP, _Float16* __restrict__ gP) {
  int p = blockIdx.y;
  int b = blockIdx.z;
  int sp0 = blockIdx.x * 64;
  int tid = threadIdx.x;
  int w = tid >> 6;
  int lane = tid & 63;
  int l31 = lane & 31;
  int h = lane >> 5;
  const _Float16* xPb = xP + (size_t)b * HW_ * C_;
  f32x16 acc[2];
#pragma unroll
  for (int i = 0; i < 2; ++i)
#pragma unroll
    for (int j = 0; j < 16; ++j) acc[i][j] = 0.f;

  if (p < 2) {
    int wsp = w & 1, wci = w >> 1;
    const _Float16* W = w16 + (size_t)p * 32768;
#pragma unroll
    for (int ks = 0; ks < 16; ++ks) {
      int k8 = ks * 2 + h;
      f16x8 bf = *(const f16x8*)&xPb[((((sp0 >> 5) + wsp) * 32 + k8) * 32 + l31) * 8];
#pragma unroll
      for (int mt = 0; mt < 2; ++mt) {
        f16x8 af = *(const f16x8*)&W[((((wci * 2 + mt) * 32) + k8) * 32 + l31) * 8];
        acc[mt] = mfma16(af, bf, acc[mt]);
      }
    }
    const float* bias = (p == 0) ? tb : pb;
    float bscl = (p == 0) ? LOG2E : 1.f;
    _Float16* out = ((p == 0) ? thetaP : phiP) + (size_t)b * HW_ * CI_;
    int sp = sp0 + wsp * 32 + l31;
#pragma unroll
    for (int mt = 0; mt < 2; ++mt)
#pragma unroll
      for (int g4 = 0; g4 < 4; ++g4) {
        int cb = (wci * 2 + mt) * 32 + g4 * 8 + h * 4;
        f32x4 bv = *(const f32x4*)&bias[cb];
        f16x4 res = pk4(acc[mt][g4 * 4 + 0] + bv[0] * bscl,
                        acc[mt][g4 * 4 + 1] + bv[1] * bscl,
                        acc[mt][g4 * 4 + 2] + bv[2] * bscl,
                        acc[mt][g4 * 4 + 3] + bv[3] * bscl);
        size_t off8 = ((size_t)(sp >> 5) * (CI_ / 4) + (cb >> 2)) * 32 + (sp & 31);
        *(f16x4*)&out[off8 * 4] = res;
      }
  } else {
    int wci = w;  // 0..3
    const _Float16* W = w16 + 2 * 32768;
#pragma unroll
    for (int ks = 0; ks < 16; ++ks) {
      int k8 = ks * 2 + h;
      f16x8 bf = *(const f16x8*)&W[((wci * 32 + k8) * 32 + l31) * 8];
#pragma unroll
      for (int mt = 0; mt < 2; ++mt) {
        f16x8 af = *(const f16x8*)&xPb[((((sp0 >> 5) + mt) * 32 + k8) * 32 + l31) * 8];
        acc[mt] = mfma16(af, bf, acc[mt]);
      }
    }
    float bv = gb[wci * 32 + l31];
    _Float16* out = gP + (size_t)b * CI_ * HW_;
#pragma unroll
    for (int mt = 0; mt < 2; ++mt)
#pragma unroll
      for (int g4 = 0; g4 < 4; ++g4) {
        int key4 = (sp0 >> 2) + mt * 8 + g4 * 2 + h;
        f16x4 res = pk4(acc[mt][g4 * 4 + 0] + bv, acc[mt][g4 * 4 + 1] + bv,
                        acc[mt][g4 * 4 + 2] + bv, acc[mt][g4 * 4 + 3] + bv);
        size_t off8 = ((size_t)wci * (HW_ / 4) + key4) * 32 + l31;
        *(f16x4*)&out[off8 * 4] = res;
      }
  }
}

// ---------------- K2: flash attention, reg-prefetch pipeline, shuffle P-exchange --------
__global__ __launch_bounds__(256, 2) void k2_attn(
    const _Float16* __restrict__ thetaP, const _Float16* __restrict__ phiP,
    const _Float16* __restrict__ gP, _Float16* __restrict__ Opart,
    float* __restrict__ ml) {
  __shared__ _Float16 ldsPhi[8192];  // 16 KB: 64 keys x 128 ci, packed
  __shared__ _Float16 ldsG[8192];    // 16 KB: 128 ci x 64 keys, packed
  int s = blockIdx.y;
  int b = blockIdx.z;
  int q0 = blockIdx.x * 128;
  int tid = threadIdx.x;
  int w = tid >> 6;
  int lane = tid & 63;
  int l31 = lane & 31;
  int h = lane >> 5;
  int qblk = (q0 >> 5) + w;
  const _Float16* thb = thetaP + (size_t)b * HW_ * CI_;
  const _Float16* phb = phiP + (size_t)b * HW_ * CI_;
  const _Float16* gvb = gP + (size_t)b * CI_ * HW_;

  f16x8 Bq[8];
#pragma unroll
  for (int ks = 0; ks < 8; ++ks) {
    f16x4 lo = *(const f16x4*)&thb[(((size_t)qblk * 32 + ks * 4 + h * 2) * 32 + l31) * 4];
    f16x4 hi = *(const f16x4*)&thb[(((size_t)qblk * 32 + ks * 4 + h * 2 + 1) * 32 + l31) * 4];
    Bq[ks] = cat8(lo, hi);
  }

  f32x16 o[4];
#pragma unroll
  for (int i = 0; i < 4; ++i)
#pragma unroll
    for (int j = 0; j < 16; ++j) o[i][j] = 0.f;
  float m_run = -1e30f, l_run = 0.f;

  f16x8 pf[8];
  auto load_pf = [&](int kb) {
    const _Float16* phiSrc = phb + (size_t)(kb >> 5) * 4096;
#pragma unroll
    for (int i = 0; i < 8; ++i) {
      int cc = w * 8 + i;
      if (cc < 16) {
        pf[i] = *(const f16x8*)&phiSrc[cc * 512 + lane * 8];
      } else {
        int j = cc - 16, seg = j >> 2, wi = j & 3;
        pf[i] = *(const f16x8*)&gvb[((size_t)seg * (HW_ / 4) + (kb >> 2)) * 128 +
                                    wi * 512 + lane * 8];
      }
    }
  };

  load_pf(s * 1024);

  for (int t = 0; t < 16; ++t) {
    // ---- commit prefetched tile to LDS ----
#pragma unroll
    for (int i = 0; i < 8; ++i) {
      int cc = w * 8 + i;
      if (cc < 16)
        *(f16x8*)&ldsPhi[cc * 512 + lane * 8] = pf[i];
      else
        *(f16x8*)&ldsG[(cc - 16) * 512 + lane * 8] = pf[i];
    }
    __syncthreads();
    // ---- issue next tile's global loads (latency hidden behind compute) ----
    if (t < 15) load_pf(s * 1024 + (t + 1) * 64);
    // ---- QK^T (S^T): A = phi rows (key), B = theta (q) ----
    f32x16 sT[2];
#pragma unroll
    for (int i = 0; i < 2; ++i)
#pragma unroll
      for (int j = 0; j < 16; ++j) sT[i][j] = 0.f;
#pragma unroll
    for (int ks = 0; ks < 8; ++ks) {
#pragma unroll
      for (int mt = 0; mt < 2; ++mt) {
        const _Float16* pb2 = ldsPhi + mt * 4096;
        f16x4 lo = *(const f16x4*)&pb2[((ks * 4 + h * 2) * 32 + l31) * 4];
        f16x4 hi = *(const f16x4*)&pb2[((ks * 4 + h * 2 + 1) * 32 + l31) * 4];
        sT[mt] = mfma16(cat8(lo, hi), Bq[ks], sT[mt]);
      }
    }
    // ---- online softmax, log2 domain (theta pre-scaled by log2e) ----
    float vmax = -1e30f;
#pragma unroll
    for (int mt = 0; mt < 2; ++mt)
#pragma unroll
      for (int r = 0; r < 16; ++r) vmax = fmaxf(vmax, sT[mt][r]);
    vmax = fmaxf(vmax, __shfl_xor(vmax, 32, 64));
    float m_new = fmaxf(m_run, vmax);
    float alpha = exp2f(m_run - m_new);
    float psum = 0.f;
#pragma unroll
    for (int mt = 0; mt < 2; ++mt)
#pragma unroll
      for (int r = 0; r < 16; ++r) {
        float pv = exp2f(sT[mt][r] - m_new);
        sT[mt][r] = pv;
        psum += pv;
      }
    psum += __shfl_xor(psum, 32, 64);
    l_run = l_run * alpha + psum;
    m_run = m_new;
#pragma unroll
    for (int i = 0; i < 4; ++i)
#pragma unroll
      for (int j = 0; j < 16; ++j) o[i][j] *= alpha;
    // ---- P: C-layout -> B-operand via cross-half shuffle (no LDS) ----
    f16x8 pfrag[4];
#pragma unroll
    for (int mt = 0; mt < 2; ++mt)
#pragma unroll
      for (int k2i = 0; k2i < 2; ++k2i) {
        int rb = k2i * 8;
        f16x4 A0 = pk4(sT[mt][rb + 0], sT[mt][rb + 1], sT[mt][rb + 2], sT[mt][rb + 3]);
        f16x4 A1 = pk4(sT[mt][rb + 4], sT[mt][rb + 5], sT[mt][rb + 6], sT[mt][rb + 7]);
        QW snd;
        snd.v = h ? A0 : A1;  // h=0 sends 8..11, h=1 sends 4..7
        QW rcv;
        rcv.q = __shfl_xor(snd.q, 32, 64);
        pfrag[mt * 2 + k2i] = h ? cat8(rcv.v, A1) : cat8(A0, rcv.v);
      }
    // ---- PV: O^T += g (ci) x P^T (q) ----
#pragma unroll
    for (int kv = 0; kv < 4; ++kv) {
#pragma unroll
      for (int mt2 = 0; mt2 < 4; ++mt2) {
        const _Float16* gb2 = ldsG + mt2 * 2048;
        f16x4 lo = *(const f16x4*)&gb2[((kv * 4 + h * 2) * 32 + l31) * 4];
        f16x4 hi = *(const f16x4*)&gb2[((kv * 4 + h * 2 + 1) * 32 + l31) * 4];
        o[mt2] = mfma16(cat8(lo, hi), pfrag[kv], o[mt2]);
      }
    }
    __syncthreads();
  }
  // ---- epilogue: normalized partial O in packed (row=q, k=ci, 8B) layout ----
  float inv = 1.f / l_run;
  int S = b * KS_ + s;
  size_t obase = (size_t)S * (HW_ * CI_ / 4);
#pragma unroll
  for (int mt2 = 0; mt2 < 4; ++mt2)
#pragma unroll
    for (int g4 = 0; g4 < 4; ++g4) {
      f16x4 res = pk4(o[mt2][g4 * 4 + 0] * inv, o[mt2][g4 * 4 + 1] * inv,
                      o[mt2][g4 * 4 + 2] * inv, o[mt2][g4 * 4 + 3] * inv);
      int ci4 = mt2 * 8 + g4 * 2 + h;
      size_t off8 = obase + ((size_t)qblk * 32 + ci4) * 32 + l31;
      *(f16x4*)&Opart[off8 * 4] = res;
    }
  if (h == 0) {
    int q = qblk * 32 + l31;
    *(float2*)&ml[((size_t)S * HW_ + q) * 2] = make_float2(m_run, l_run);
  }
}

// ---------------- K3: split-merge + out conv fused -> oc16 (f16) ----------------
__global__ __launch_bounds__(256, 2) void k3_outconv(
    const _Float16* __restrict__ Opart, const float* __restrict__ ml,
    const _Float16* __restrict__ wo, const float* __restrict__ ob,
    _Float16* __restrict__ oc16) {
  int b = blockIdx.z;
  int c0 = blockIdx.y * 128;
  int s0 = blockIdx.x * 64;
  int tid = threadIdx.x;
  int w = tid >> 6;
  int lane = tid & 63;
  int l31 = lane & 31;
  int h = lane >> 5;
  int wsp = w & 1, wc = w >> 1;
  int qblk = (s0 >> 5) + wsp;
  int sp = s0 + wsp * 32 + l31;
  // per-lane merge weights (lane's B-row sp is fixed)
  float m[KS_], l[KS_], M = -1e30f;
#pragma unroll
  for (int s = 0; s < KS_; ++s) {
    float2 v = *(const float2*)&ml[((size_t)(b * KS_ + s) * HW_ + sp) * 2];
    m[s] = v.x;
    l[s] = v.y;
    M = fmaxf(M, m[s]);
  }
  float den = 0.f, wgt[KS_];
#pragma unroll
  for (int s = 0; s < KS_; ++s) {
    wgt[s] = exp2f(m[s] - M) * l[s];
    den += wgt[s];
  }
  float inv = 1.f / den;
  f16x2 wh[KS_];
#pragma unroll
  for (int s = 0; s < KS_; ++s) {
    _Float16 ws = (_Float16)(wgt[s] * inv);
    wh[s][0] = ws;
    wh[s][1] = ws;
  }
  f32x16 acc[2];
#pragma unroll
  for (int i = 0; i < 2; ++i)
#pragma unroll
    for (int j = 0; j < 16; ++j) acc[i][j] = 0.f;
#pragma unroll
  for (int ks = 0; ks < 8; ++ks) {
    int k8 = ks * 2 + h;
    // merge 4 splits into attn B-fragment (8 ci values) with packed f16 fma
    F4 a0, a1;
    a0.h2[0] = f16x2{0, 0}; a0.h2[1] = f16x2{0, 0};
    a1.h2[0] = f16x2{0, 0}; a1.h2[1] = f16x2{0, 0};
#pragma unroll
    for (int s = 0; s < KS_; ++s) {
      size_t base = (size_t)(b * KS_ + s) * (HW_ * CI_ / 4) +
                    ((size_t)qblk * 32 + k8 * 2) * 32 + l31;
      F4 v0, v1;
      v0.v = *(const f16x4*)&Opart[base * 4];
      v1.v = *(const f16x4*)&Opart[(base + 32) * 4];
      a0.h2[0] += wh[s] * v0.h2[0];
      a0.h2[1] += wh[s] * v0.h2[1];
      a1.h2[0] += wh[s] * v1.h2[0];
      a1.h2[1] += wh[s] * v1.h2[1];
    }
    f16x8 bf = cat8(a0.v, a1.v);
#pragma unroll
    for (int mt = 0; mt < 2; ++mt) {
      int rblk = (c0 >> 5) + (wc * 2 + mt);
      f16x8 af = *(const f16x8*)&wo[((rblk * 16 + k8) * 32 + l31) * 8];
      acc[mt] = mfma16(af, bf, acc[mt]);
    }
  }
#pragma unroll
  for (int mt = 0; mt < 2; ++mt)
#pragma unroll
    for (int r = 0; r < 16; ++r) {
      int c = c0 + (wc * 2 + mt) * 32 + (r & 3) + 8 * (r >> 2) + 4 * h;
      oc16[((size_t)(b * C_ + c)) * HW_ + sp] = (_Float16)(acc[mt][r] + ob[c]);
    }
}

// ---------------- K3b: BN stats from f16 oc, one block per channel ----------------
__global__ __launch_bounds__(256) void k3b_bnstats(const _Float16* __restrict__ oc16,
                                                   float* __restrict__ bnsum) {
  int c = blockIdx.x;
  int t = threadIdx.x;
  float s = 0.f, s2 = 0.f;
#pragma unroll
  for (int b = 0; b < B_; ++b) {
    const _Float16* p = oc16 + ((size_t)(b * C_ + c)) * HW_;
#pragma unroll
    for (int i = 0; i < 2; ++i) {
      f16x8 v = *(const f16x8*)&p[t * 8 + i * 2048];
#pragma unroll
      for (int j = 0; j < 8; ++j) {
        float f = (float)v[j];
        s += f;
        s2 += f * f;
      }
    }
  }
#pragma unroll
  for (int m = 1; m < 64; m <<= 1) {
    s += __shfl_xor(s, m, 64);
    s2 += __shfl_xor(s2, m, 64);
  }
  __shared__ float ls[8];
  int w = t >> 6, lane = t & 63;
  if (lane == 0) {
    ls[w] = s;
    ls[4 + w] = s2;
  }
  __syncthreads();
  if (t == 0) {
    bnsum[c] = ls[0] + ls[1] + ls[2] + ls[3];
    bnsum[C_ + c] = ls[4] + ls[5] + ls[6] + ls[7];
  }
}

// ---------------- K4: BN (training stats) + ReLU + residual ----------------
__global__ __launch_bounds__(256) void k4_final(
    const _Float16* __restrict__ oc16, const float* __restrict__ x,
    const float* __restrict__ bnsum, const float* __restrict__ gamma,
    const float* __restrict__ beta, float* __restrict__ out) {
  int gid = blockIdx.x * 256 + threadIdx.x;
  size_t base = (size_t)gid * 4;
  int c = (int)((base >> 12) & 255);
  float mean = bnsum[c] * (1.f / 16384.f);
  float var = bnsum[C_ + c] * (1.f / 16384.f) - mean * mean;
  float sc = gamma[c] * rsqrtf(var + 1e-5f);
  float bt = beta[c];
  f16x4 v16 = *(const f16x4*)&oc16[base];
  f32x4 xv = *(const f32x4*)&x[base];
  f32x4 r;
#pragma unroll
  for (int j = 0; j < 4; ++j) {
    float y = ((float)v16[j] - mean) * sc + bt;
    y = fmaxf(y, 0.f);
    r[j] = y + xv[j];
  }
  *(f32x4*)&out[base] = r;
}

extern "C" void kernel_launch(void* const* d_in, const int* in_sizes, int n_in,
                              void* d_out, int out_size, void* d_ws,
                              size_t ws_size, hipStream_t stream) {
  const float* x = (const float*)d_in[0];
  const float* g_w = (const float*)d_in[1];
  const float* g_b = (const float*)d_in[2];
  const float* th_w = (const float*)d_in[3];
  const float* th_b = (const float*)d_in[4];
  const float* ph_w = (const float*)d_in[5];
  const float* ph_b = (const float*)d_in[6];
  const float* o_w = (const float*)d_in[7];
  const float* o_b = (const float*)d_in[8];
  const float* gam = (const float*)d_in[9];
  const float* bet = (const float*)d_in[10];

  char* ws = (char*)d_ws;
  _Float16* xP = (_Float16*)ws;                      // 8 MB (dead after k1; reused as oc16)
  _Float16* oc16 = (_Float16*)ws;                    // 8 MB f16 out-conv result
  _Float16* thetaP = (_Float16*)(ws + 8388608);      // 4 MB
  _Float16* phiP = (_Float16*)(ws + 12582912);       // 4 MB
  _Float16* gP = (_Float16*)(ws + 16777216);         // 4 MB
  _Float16* w16 = (_Float16*)(ws + 25165824);        // 256 KB
  float* ml = (float*)(ws + 25427968);               // 512 KB
  float* bn = (float*)(ws + 25952256);               // 2 KB
  _Float16* Opart = (_Float16*)d_out;  // 16 MB scratch; k3 consumes, k4 overwrites

  k0_prep<<<dim3(64, 4, 4), 256, 0, stream>>>(x, xP, th_w, ph_w, g_w, o_w, w16);
  k1_proj<<<dim3(64, 3, 4), 256, 0, stream>>>(xP, w16, th_b, ph_b, g_b, thetaP,
                                              phiP, gP);
  k2_attn<<<dim3(32, KS_, 4), 256, 0, stream>>>(thetaP, phiP, gP, Opart, ml);
  k3_outconv<<<dim3(64, 2, 4), 256, 0, stream>>>(Opart, ml, w16 + 3 * 32768, o_b,
                                                 oc16);
  k3b_bnstats<<<256, 256, 0, stream>>>(oc16, bn);
  k4_final<<<4096, 256, 0, stream>>>(oc16, x, bn, gam, bet, (float*)d_out);
}